// Round 1
// baseline (31.454 us; speedup 1.0000x reference)
//
#include <hip/hip_runtime.h>

typedef __attribute__((ext_vector_type(8))) short short8;
typedef __attribute__((ext_vector_type(4))) float f32x4;
typedef __attribute__((ext_vector_type(2))) unsigned u32x2;
typedef __attribute__((ext_vector_type(4))) unsigned u32x4;

#define XSTR 72  // padded LDS row stride in bf16 elements (144 B)

__device__ __forceinline__ unsigned f2bf(float f) {
    unsigned u = __float_as_uint(f);
    return (u + 0x7fffu + ((u >> 16) & 1u)) >> 16;  // RNE float->bf16 bits
}
__device__ __forceinline__ unsigned pack2(float lo, float hi) {
    return f2bf(lo) | (f2bf(hi) << 16);
}

// x: (64, 2, 64, 64, 64) f32 ; W: (32, 32, 64, 128) f32 ; out: (64, 2, 32, 32, 128) f32
__global__ __launch_bounds__(256) void cplx_dot_kernel(
    const float* __restrict__ x, const float* __restrict__ Wr,
    const float* __restrict__ Wi, const float* __restrict__ br,
    const float* __restrict__ bi, float* __restrict__ out)
{
    __shared__ __align__(16) short sXr[64 * XSTR];
    __shared__ __align__(16) short sXi[64 * XSTR];
    __shared__ __align__(16) short sWr[128 * XSTR];
    __shared__ __align__(16) short sWi[128 * XSTR];

    const int bid = blockIdx.x;          // 0..1023
    const int h = bid >> 5, w = bid & 31;
    const int t = threadIdx.x;

    // ---- stage x crop -> LDS bf16 [b][c], rows padded to 72 ----
    #pragma unroll
    for (int i = 0; i < 4; ++i) {
        int idx = t + 256 * i;           // 0..1023  (64 b-rows x 16 float4)
        int b = idx >> 4, q = idx & 15;
        size_t g = ((((size_t)b * 2) * 64 + (16 + h)) * 64 + (16 + w)) * 64 + q * 4;
        f32x4 vr = *(const f32x4*)(x + g);
        f32x4 vi = *(const f32x4*)(x + g + (size_t)64 * 64 * 64);
        u32x2 pr, pi;
        pr[0] = pack2(vr[0], vr[1]); pr[1] = pack2(vr[2], vr[3]);
        pi[0] = pack2(vi[0], vi[1]); pi[1] = pack2(vi[2], vi[3]);
        *(u32x2*)&sXr[b * XSTR + q * 4] = pr;
        *(u32x2*)&sXi[b * XSTR + q * 4] = pi;
    }

    // ---- stage W slice -> LDS bf16 transposed [f][c] ----
    {
        const int g = t & 31, cg = t >> 5;   // g: float4 group along f ; cg: c-octet
        const size_t wbase = (((size_t)h * 32 + w) * 64) * 128;
        f32x4 rr[8], ri[8];
        #pragma unroll
        for (int i = 0; i < 8; ++i) {
            size_t off = wbase + (size_t)(8 * cg + i) * 128 + 4 * g;
            rr[i] = *(const f32x4*)(Wr + off);
            ri[i] = *(const f32x4*)(Wi + off);
        }
        #pragma unroll
        for (int j = 0; j < 4; ++j) {        // column f = 4g+j, c = 8cg..8cg+7
            u32x4 pr, pi;
            pr[0] = pack2(rr[0][j], rr[1][j]); pr[1] = pack2(rr[2][j], rr[3][j]);
            pr[2] = pack2(rr[4][j], rr[5][j]); pr[3] = pack2(rr[6][j], rr[7][j]);
            pi[0] = pack2(ri[0][j], ri[1][j]); pi[1] = pack2(ri[2][j], ri[3][j]);
            pi[2] = pack2(ri[4][j], ri[5][j]); pi[3] = pack2(ri[6][j], ri[7][j]);
            *(u32x4*)&sWr[(4 * g + j) * XSTR + 8 * cg] = pr;
            *(u32x4*)&sWi[(4 * g + j) * XSTR + 8 * cg] = pi;
        }
    }
    __syncthreads();

    // ---- MFMA compute: wave wv owns b-rows [16wv, 16wv+16), all 128 f ----
    const int wv = t >> 6, l = t & 63;
    const int lr = l & 15, lh = l >> 4;

    f32x4 accR[8], accI[8];
    #pragma unroll
    for (int ft = 0; ft < 8; ++ft) {
        #pragma unroll
        for (int j = 0; j < 4; ++j) { accR[ft][j] = 0.f; accI[ft][j] = 0.f; }
    }

    #pragma unroll
    for (int kk = 0; kk < 2; ++kk) {
        const int c0 = 32 * kk + 8 * lh;     // lane's k-offset (8 contiguous)
        short8 ar = *(const short8*)&sXr[(16 * wv + lr) * XSTR + c0];
        short8 ai = *(const short8*)&sXi[(16 * wv + lr) * XSTR + c0];
        short8 an;
        #pragma unroll
        for (int j = 0; j < 8; ++j) an[j] = ai[j] ^ (short)0x8000;  // -xi
        #pragma unroll
        for (int ft = 0; ft < 8; ++ft) {
            short8 wr_ = *(const short8*)&sWr[(16 * ft + lr) * XSTR + c0];
            short8 wi_ = *(const short8*)&sWi[(16 * ft + lr) * XSTR + c0];
            accR[ft] = __builtin_amdgcn_mfma_f32_16x16x32_bf16(ar, wr_, accR[ft], 0, 0, 0);
            accR[ft] = __builtin_amdgcn_mfma_f32_16x16x32_bf16(an, wi_, accR[ft], 0, 0, 0);
            accI[ft] = __builtin_amdgcn_mfma_f32_16x16x32_bf16(ar, wi_, accI[ft], 0, 0, 0);
            accI[ft] = __builtin_amdgcn_mfma_f32_16x16x32_bf16(ai, wr_, accI[ft], 0, 0, 0);
        }
    }

    // ---- epilogue: bias + relu + store (C/D: col=lane&15, row=(lane>>4)*4+j) ----
    #pragma unroll
    for (int ft = 0; ft < 8; ++ft) {
        const int fc = 16 * ft + lr;
        const float vbr = br[fc], vbi = bi[fc];
        #pragma unroll
        for (int j = 0; j < 4; ++j) {
            const int b = 16 * wv + 4 * lh + j;
            size_t o = ((((size_t)b * 2) * 32 + h) * 32 + w) * 128 + fc;
            out[o] = fmaxf(accR[ft][j] + vbr, 0.f);
            out[o + (size_t)32 * 32 * 128] = fmaxf(accI[ft][j] + vbi, 0.f);
        }
    }
}

extern "C" void kernel_launch(void* const* d_in, const int* in_sizes, int n_in,
                              void* d_out, int out_size, void* d_ws, size_t ws_size,
                              hipStream_t stream) {
    const float* x  = (const float*)d_in[0];
    const float* Wr = (const float*)d_in[1];
    const float* Wi = (const float*)d_in[2];
    const float* br = (const float*)d_in[3];
    const float* bi = (const float*)d_in[4];
    float* out = (float*)d_out;
    hipLaunchKernelGGL(cplx_dot_kernel, dim3(1024), dim3(256), 0, stream,
                       x, Wr, Wi, br, bi, out);
}

// Round 2
// 30.699 us; speedup vs baseline: 1.0246x; 1.0246x over previous
//
#include <hip/hip_runtime.h>

typedef __attribute__((ext_vector_type(8))) short short8;
typedef __attribute__((ext_vector_type(4))) float f32x4;
typedef __attribute__((ext_vector_type(4))) unsigned u32x4;

#define XSTR 72  // padded LDS row stride in bf16 elements (144 B)

__device__ __forceinline__ unsigned f2bf(float f) {
    unsigned u = __float_as_uint(f);
    return (u + 0x7fffu + ((u >> 16) & 1u)) >> 16;  // RNE float->bf16 bits
}
__device__ __forceinline__ unsigned pack2(float lo, float hi) {
    return f2bf(lo) | (f2bf(hi) << 16);
}

// x: (64, 2, 64, 64, 64) f32 ; W: (32, 32, 64, 128) f32 ; out: (64, 2, 32, 32, 128) f32
__global__ __launch_bounds__(256, 4) void cplx_dot_kernel(
    const float* __restrict__ x, const float* __restrict__ Wr,
    const float* __restrict__ Wi, const float* __restrict__ br,
    const float* __restrict__ bi, float* __restrict__ out)
{
    __shared__ __align__(16) short sWr[128 * XSTR];
    __shared__ __align__(16) short sWi[128 * XSTR];

    const int bid = blockIdx.x;          // 0..1023
    const int h = bid >> 5, w = bid & 31;
    const int t = threadIdx.x;
    const int wv = t >> 6, l = t & 63;
    const int lr = l & 15, lh = l >> 4;

    // ---- A-fragments: direct global -> reg (issued first, in flight during W staging)
    // wave wv owns b-rows [16wv,16wv+16); lane (lr,lh) needs x[16wv+lr][c0..c0+8], c0=32kk+8lh
    const int brow = 16 * wv + lr;
    const size_t gx = ((((size_t)brow * 2) * 64 + (16 + h)) * 64 + (16 + w)) * 64;
    const size_t gimg = (size_t)64 * 64 * 64;  // re->im offset in floats

    f32x4 vr[2][2], vi[2][2];
    #pragma unroll
    for (int kk = 0; kk < 2; ++kk) {
        const int c0 = 32 * kk + 8 * lh;
        vr[kk][0] = *(const f32x4*)(x + gx + c0);
        vr[kk][1] = *(const f32x4*)(x + gx + c0 + 4);
        vi[kk][0] = *(const f32x4*)(x + gx + gimg + c0);
        vi[kk][1] = *(const f32x4*)(x + gx + gimg + c0 + 4);
    }
    u32x4 ar[2], ai[2];
    #pragma unroll
    for (int kk = 0; kk < 2; ++kk) {
        #pragma unroll
        for (int p = 0; p < 2; ++p) {
            ar[kk][2 * p]     = pack2(vr[kk][p][0], vr[kk][p][1]);
            ar[kk][2 * p + 1] = pack2(vr[kk][p][2], vr[kk][p][3]);
            ai[kk][2 * p]     = pack2(vi[kk][p][0], vi[kk][p][1]);
            ai[kk][2 * p + 1] = pack2(vi[kk][p][2], vi[kk][p][3]);
        }
    }

    // ---- stage W slice -> LDS bf16 transposed [f][c] ----
    {
        const int g = t & 31, cg = t >> 5;   // g: float4 group along f ; cg: c-octet
        const size_t wbase = (((size_t)h * 32 + w) * 64) * 128;
        f32x4 rr[8], ri[8];
        #pragma unroll
        for (int i = 0; i < 8; ++i) {
            size_t off = wbase + (size_t)(8 * cg + i) * 128 + 4 * g;
            rr[i] = *(const f32x4*)(Wr + off);
            ri[i] = *(const f32x4*)(Wi + off);
        }
        #pragma unroll
        for (int j = 0; j < 4; ++j) {        // column f = 4g+j, c = 8cg..8cg+7
            u32x4 pr, pi;
            pr[0] = pack2(rr[0][j], rr[1][j]); pr[1] = pack2(rr[2][j], rr[3][j]);
            pr[2] = pack2(rr[4][j], rr[5][j]); pr[3] = pack2(rr[6][j], rr[7][j]);
            pi[0] = pack2(ri[0][j], ri[1][j]); pi[1] = pack2(ri[2][j], ri[3][j]);
            pi[2] = pack2(ri[4][j], ri[5][j]); pi[3] = pack2(ri[6][j], ri[7][j]);
            *(u32x4*)&sWr[(4 * g + j) * XSTR + 8 * cg] = pr;
            *(u32x4*)&sWi[(4 * g + j) * XSTR + 8 * cg] = pi;
        }
    }
    __syncthreads();

    // ---- MFMA compute ----
    f32x4 accR[8], accI[8];
    #pragma unroll
    for (int ft = 0; ft < 8; ++ft) {
        #pragma unroll
        for (int j = 0; j < 4; ++j) { accR[ft][j] = 0.f; accI[ft][j] = 0.f; }
    }

    #pragma unroll
    for (int kk = 0; kk < 2; ++kk) {
        const int c0 = 32 * kk + 8 * lh;
        short8 arf = __builtin_bit_cast(short8, ar[kk]);
        short8 aif = __builtin_bit_cast(short8, ai[kk]);
        short8 anf;
        #pragma unroll
        for (int j = 0; j < 8; ++j) anf[j] = aif[j] ^ (short)0x8000;  // -xi
        #pragma unroll
        for (int ft = 0; ft < 8; ++ft) {
            short8 wr_ = *(const short8*)&sWr[(16 * ft + lr) * XSTR + c0];
            short8 wi_ = *(const short8*)&sWi[(16 * ft + lr) * XSTR + c0];
            accR[ft] = __builtin_amdgcn_mfma_f32_16x16x32_bf16(arf, wr_, accR[ft], 0, 0, 0);
            accR[ft] = __builtin_amdgcn_mfma_f32_16x16x32_bf16(anf, wi_, accR[ft], 0, 0, 0);
            accI[ft] = __builtin_amdgcn_mfma_f32_16x16x32_bf16(arf, wi_, accI[ft], 0, 0, 0);
            accI[ft] = __builtin_amdgcn_mfma_f32_16x16x32_bf16(aif, wr_, accI[ft], 0, 0, 0);
        }
    }

    // ---- epilogue: bias + relu + store (C/D: col=lane&15, row=(lane>>4)*4+j) ----
    #pragma unroll
    for (int ft = 0; ft < 8; ++ft) {
        const int fc = 16 * ft + lr;
        const float vbr = br[fc], vbi = bi[fc];
        #pragma unroll
        for (int j = 0; j < 4; ++j) {
            const int b = 16 * wv + 4 * lh + j;
            size_t o = ((((size_t)b * 2) * 32 + h) * 32 + w) * 128 + fc;
            out[o] = fmaxf(accR[ft][j] + vbr, 0.f);
            out[o + (size_t)32 * 32 * 128] = fmaxf(accI[ft][j] + vbi, 0.f);
        }
    }
}

extern "C" void kernel_launch(void* const* d_in, const int* in_sizes, int n_in,
                              void* d_out, int out_size, void* d_ws, size_t ws_size,
                              hipStream_t stream) {
    const float* x  = (const float*)d_in[0];
    const float* Wr = (const float*)d_in[1];
    const float* Wi = (const float*)d_in[2];
    const float* br = (const float*)d_in[3];
    const float* bi = (const float*)d_in[4];
    float* out = (float*)d_out;
    hipLaunchKernelGGL(cplx_dot_kernel, dim3(1024), dim3(256), 0, stream,
                       x, Wr, Wi, br, bi, out);
}